// Round 1
// 906.367 us; speedup vs baseline: 1.0757x; 1.0757x over previous
//
#include <hip/hip_runtime.h>
#include <hip/hip_bf16.h>

#define BB 4
#define TT 4096
#define DD 2048
#define BOTC 256

typedef __bf16 bf16;
typedef __attribute__((ext_vector_type(4))) __bf16 bf16x4;
typedef __attribute__((ext_vector_type(8))) __bf16 bf16x8;
typedef __attribute__((ext_vector_type(4))) float f32x4;

constexpr int BM = 128, BN = 128, BK = 64;

__device__ __forceinline__ void async16(const void* g, bf16* l) {
  __builtin_amdgcn_global_load_lds((const __attribute__((address_space(1))) void*)g,
                                   (__attribute__((address_space(3))) void*)l, 16, 0, 0);
}

#define SBAR asm volatile("s_barrier" ::: "memory")
#define WAIT_LGKM0 asm volatile("s_waitcnt lgkmcnt(0)" ::: "memory")
#define WAIT_VM6 asm volatile("s_waitcnt vmcnt(6)" ::: "memory")
#define WAIT_VM0 asm volatile("s_waitcnt vmcnt(0)" ::: "memory")

// ---------------- 128x128 tile GEMM (projection EPI=1, scores EPI=2) ----------------
// C[m,n] = sum_k A[m,k]*B[n,k]  (row-major, K contiguous; ldA/ldB row strides)
template <int EPI>
__global__ __launch_bounds__(256) void gemm_bt(
    const bf16* __restrict__ A, const bf16* __restrict__ Bm, void* __restrict__ Cout,
    const float* __restrict__ bias, int M, int N, int K, int ldA, int ldB,
    long sAb, long sBb, long sCb, float scale) {
  const int b = blockIdx.z;
  const int m0 = blockIdx.y * BM;
  const int n0 = blockIdx.x * BN;
  const int tid = threadIdx.x;
  const int lane = tid & 63;
  const int w = tid >> 6;
  const int wm = (w >> 1) * 64;
  const int wn = (w & 1) * 64;

  if (EPI == 2 && n0 > m0) return;  // fully masked: never written, never read

  __shared__ bf16 As[BM * BK];
  __shared__ bf16 Bs[BN * BK];

  f32x4 acc[4][4] = {};

  const bf16* Arow = A + (size_t)b * sAb + (size_t)m0 * ldA;
  const bf16* Brow = Bm + (size_t)b * sBb + (size_t)n0 * ldB;

  for (int k0 = 0; k0 < K; k0 += BK) {
#pragma unroll
    for (int j = 0; j < 4; ++j) {
      int c = j * 256 + tid;
      int row = c >> 3, kc = c & 7;
      int gk = kc ^ (row & 7);
      async16(Arow + (size_t)row * ldA + k0 + gk * 8, As + (size_t)c * 8);
      async16(Brow + (size_t)row * ldB + k0 + gk * 8, Bs + (size_t)c * 8);
    }
    __syncthreads();
    bf16x8 af[4][2], bfr[4][2];
#pragma unroll
    for (int mi = 0; mi < 4; ++mi)
#pragma unroll
      for (int kk = 0; kk < 2; ++kk) {
        int row = wm + mi * 16 + (lane & 15);
        int kc = kk * 4 + (lane >> 4);
        af[mi][kk] = *(const bf16x8*)(As + ((size_t)row * 8 + (kc ^ (row & 7))) * 8);
      }
#pragma unroll
    for (int ni = 0; ni < 4; ++ni)
#pragma unroll
      for (int kk = 0; kk < 2; ++kk) {
        int row = wn + ni * 16 + (lane & 15);
        int kc = kk * 4 + (lane >> 4);
        bfr[ni][kk] = *(const bf16x8*)(Bs + ((size_t)row * 8 + (kc ^ (row & 7))) * 8);
      }
#pragma unroll
    for (int kk = 0; kk < 2; ++kk)
#pragma unroll
      for (int mi = 0; mi < 4; ++mi)
#pragma unroll
        for (int ni = 0; ni < 4; ++ni)
          acc[mi][ni] = __builtin_amdgcn_mfma_f32_16x16x32_bf16(af[mi][kk], bfr[ni][kk], acc[mi][ni], 0, 0, 0);
    __syncthreads();
  }

  const int lcol = lane & 15;
  const int lrow = (lane >> 4) * 4;

  if (EPI == 1) {
    bf16* C = (bf16*)Cout + (size_t)b * sCb;
#pragma unroll
    for (int mi = 0; mi < 4; ++mi) {
      int rbase = m0 + wm + mi * 16 + lrow;
#pragma unroll
      for (int ni = 0; ni < 4; ++ni) {
        int col = n0 + wn + ni * 16 + lcol;
        float bv = bias[col];
#pragma unroll
        for (int r = 0; r < 4; ++r)
          C[(size_t)(rbase + r) * N + col] = (bf16)(acc[mi][ni][r] + bv);
      }
    }
  } else {
    bf16* C = (bf16*)Cout + (size_t)b * sCb;
#pragma unroll
    for (int mi = 0; mi < 4; ++mi) {
      int rbase = m0 + wm + mi * 16 + lrow;
#pragma unroll
      for (int ni = 0; ni < 4; ++ni) {
        int col = n0 + wn + ni * 16 + lcol;
#pragma unroll
        for (int r = 0; r < 4; ++r) {
          int i = rbase + r;
          float v = acc[mi][ni][r] * scale;
          if (col > i - 4) v = -65000.0f;
          C[(size_t)i * N + col] = (bf16)v;
        }
      }
    }
  }
}

// ---------------- 256x256 8-phase GEMM (final combined @ hdc, fp32 out) ----------------
// Stage one 128x64 bf16 half-tile (16 KB): 512 threads x 2 chunks of 16B.
// Global k-chunk pre-swizzled (gk = kc ^ (row&7)); LDS dest linear (gload_lds rule).
__device__ __forceinline__ void stage_half(const bf16* __restrict__ src, int ld,
                                           bf16* lds, int tid) {
#pragma unroll
  for (int j = 0; j < 2; ++j) {
    int c = j * 512 + tid;
    int row = c >> 3;
    int gk = (c & 7) ^ (row & 7);
    async16(src + (size_t)row * ld + gk * 8, lds + (size_t)c * 8);
  }
}

__device__ __forceinline__ bf16x8 fragrd(const bf16* base, int lr, int kc) {
  return *(const bf16x8*)(base + ((size_t)lr * 8 + (kc ^ (lr & 7))) * 8);
}

__device__ __forceinline__ void load_b4(const bf16* base, int wn, int fr, int fq,
                                        bf16x8 (&bf_)[4][2]) {
#pragma unroll
  for (int ni = 0; ni < 4; ++ni)
#pragma unroll
    for (int kk = 0; kk < 2; ++kk)
      bf_[ni][kk] = fragrd(base, (wn & 1) * 64 + ni * 16 + fr, kk * 4 + fq);
}

__device__ __forceinline__ void load_a4(const bf16* base, int qm, int fr, int fq,
                                        bf16x8 (&a)[4][2]) {
#pragma unroll
  for (int mi = 0; mi < 4; ++mi)
#pragma unroll
    for (int kk = 0; kk < 2; ++kk)
      a[mi][kk] = fragrd(base, qm * 64 + mi * 16 + fr, kk * 4 + fq);
}

__device__ __forceinline__ void mfma_quad(f32x4 (&acc)[8][4], const bf16x8 (&a)[4][2],
                                          const bf16x8 (&bf_)[4][2], int qm, int qn) {
  __builtin_amdgcn_s_setprio(1);
#pragma unroll
  for (int kk = 0; kk < 2; ++kk)
#pragma unroll
    for (int mi = 0; mi < 4; ++mi)
#pragma unroll
      for (int ni = 0; ni < 2; ++ni)
        acc[qm * 4 + mi][qn * 2 + ni] = __builtin_amdgcn_mfma_f32_16x16x32_bf16(
            a[mi][kk], bf_[qn * 2 + ni][kk], acc[qm * 4 + mi][qn * 2 + ni], 0, 0, 0);
  __builtin_amdgcn_s_setprio(0);
}

// Schedule invariants (derived; see session journal):
//   reads: p0/p4 = all 8 B frags + A(qm0); p2/p6 = A(qm1)  ->
//     B halves consumed end of p0/p4, A halves end of p2/p6.
//   stage map (ht = phase+7, K-tile order B0,B1,A0,A1):
//     p0: K(2i+1).A1  p1: K(2i+2).B0  p2: K(2i+2).B1  p3: K(2i+2).A0
//     p4: K(2i+2).A1  p5: K(2i+3).B0  p6: K(2i+3).B1  p7: K(2i+3).A0
//   every write lands >=1 barrier after the region's last read.
//   vmcnt(6) at end of p3/p7 leaves exactly the 3 newest half-tiles in flight
//   and guarantees the next K-tile is fully in LDS.
__global__ __launch_bounds__(512, 2) void gemm256(
    const bf16* __restrict__ A, const bf16* __restrict__ Bm, float* __restrict__ C,
    int N, int K, int ldA, int ldB, long sAb, long sBb, long sCb) {
  const int b = blockIdx.z;
  const int m0 = blockIdx.y * 256;
  const int n0 = blockIdx.x * 256;
  const int tid = threadIdx.x;
  const int lane = tid & 63;
  const int w = tid >> 6;
  const int wm = w >> 2;   // 0..1: A half / output row half
  const int wn = w & 3;    // 0..3: output col quarter
  const int fr = lane & 15;
  const int fq = lane >> 4;
  const int bh = wn >> 1;
  const int NKT = K >> 6;  // K-tiles of 64
  const int NI = K >> 7;   // iterations (2 K-tiles each)

  __shared__ bf16 sA[2][2][8192];  // [buf][half][128*64]
  __shared__ bf16 sB[2][2][8192];

  const bf16* Ab = A + (size_t)b * sAb + (size_t)m0 * ldA;
  const bf16* Bb = Bm + (size_t)b * sBb + (size_t)n0 * ldB;

  f32x4 acc[8][4] = {};
  bf16x8 a[4][2], bf_[4][2];

  // prologue: K0 {B0,B1,A0,A1} then K1 {B0,B1,A0} = 7 half-tiles (14 loads)
  stage_half(Bb, ldB, &sB[0][0][0], tid);
  stage_half(Bb + (size_t)128 * ldB, ldB, &sB[0][1][0], tid);
  stage_half(Ab, ldA, &sA[0][0][0], tid);
  stage_half(Ab + (size_t)128 * ldA, ldA, &sA[0][1][0], tid);
  stage_half(Bb + 64, ldB, &sB[1][0][0], tid);
  stage_half(Bb + (size_t)128 * ldB + 64, ldB, &sB[1][1][0], tid);
  stage_half(Ab + 64, ldA, &sA[1][0][0], tid);
  WAIT_VM6;  // 8 oldest (= all of K0) landed
  SBAR;

  for (int i = 0; i < NI; ++i) {
    const size_t kA1 = (size_t)(2 * i + 1) * 64;
    int t2 = 2 * i + 2; if (t2 > NKT - 1) t2 = NKT - 1;  // tail clamp: redundant
    int t3 = 2 * i + 3; if (t3 > NKT - 1) t3 = NKT - 1;  // re-loads keep vmcnt exact
    const size_t k2 = (size_t)t2 * 64, k3 = (size_t)t3 * 64;

    // p0
    load_b4(&sB[0][bh][0], wn, fr, fq, bf_);
    load_a4(&sA[0][wm][0], 0, fr, fq, a);
    stage_half(Ab + (size_t)128 * ldA + kA1, ldA, &sA[1][1][0], tid);
    SBAR; WAIT_LGKM0; __builtin_amdgcn_sched_barrier(0);
    mfma_quad(acc, a, bf_, 0, 0);
    SBAR;
    // p1
    stage_half(Bb + k2, ldB, &sB[0][0][0], tid);
    SBAR;
    mfma_quad(acc, a, bf_, 0, 1);
    SBAR;
    // p2
    load_a4(&sA[0][wm][0], 1, fr, fq, a);
    stage_half(Bb + (size_t)128 * ldB + k2, ldB, &sB[0][1][0], tid);
    SBAR; WAIT_LGKM0; __builtin_amdgcn_sched_barrier(0);
    mfma_quad(acc, a, bf_, 1, 0);
    SBAR;
    // p3
    stage_half(Ab + k2, ldA, &sA[0][0][0], tid);
    SBAR;
    mfma_quad(acc, a, bf_, 1, 1);
    WAIT_VM6;  // K(2i+1) fully in LDS
    SBAR;
    // p4
    load_b4(&sB[1][bh][0], wn, fr, fq, bf_);
    load_a4(&sA[1][wm][0], 0, fr, fq, a);
    stage_half(Ab + (size_t)128 * ldA + k2, ldA, &sA[0][1][0], tid);
    SBAR; WAIT_LGKM0; __builtin_amdgcn_sched_barrier(0);
    mfma_quad(acc, a, bf_, 0, 0);
    SBAR;
    // p5
    stage_half(Bb + k3, ldB, &sB[1][0][0], tid);
    SBAR;
    mfma_quad(acc, a, bf_, 0, 1);
    SBAR;
    // p6
    load_a4(&sA[1][wm][0], 1, fr, fq, a);
    stage_half(Bb + (size_t)128 * ldB + k3, ldB, &sB[1][1][0], tid);
    SBAR; WAIT_LGKM0; __builtin_amdgcn_sched_barrier(0);
    mfma_quad(acc, a, bf_, 1, 0);
    SBAR;
    // p7
    stage_half(Ab + k3, ldA, &sA[1][0][0], tid);
    SBAR;
    mfma_quad(acc, a, bf_, 1, 1);
    WAIT_VM6;  // K(2i+2) fully in LDS
    SBAR;
  }

  WAIT_VM0;  // drain tail re-loads before epilogue

  float* Cb = C + (size_t)b * sCb;
  const int lrow = fq * 4;
#pragma unroll
  for (int mi = 0; mi < 8; ++mi) {
    int rbase = m0 + wm * 128 + mi * 16 + lrow;
#pragma unroll
    for (int ni = 0; ni < 4; ++ni) {
      int col = n0 + wn * 64 + ni * 16 + fr;
#pragma unroll
      for (int r = 0; r < 4; ++r)
        Cb[(size_t)(rbase + r) * N + col] = acc[mi][ni][r];
    }
  }
}

// fp32 [B,T,D] -> bf16 [B,T,D] and bf16 transposed [B,D,T], 64x64 tiles, wide stores
__global__ __launch_bounds__(256) void conv_transpose(
    const float* __restrict__ hdc, bf16* __restrict__ hb, bf16* __restrict__ hT) {
  __shared__ float tile[64][65];
  int b = blockIdx.z;
  int d0 = blockIdx.x * 64, t0 = blockIdx.y * 64;
  int tid = threadIdx.x;
  const float* src = hdc + (size_t)b * TT * DD;
  bf16* dstb = hb + (size_t)b * TT * DD;
  bf16* dstT = hT + (size_t)b * DD * TT;
  int c4 = tid & 15, r0 = tid >> 4;
#pragma unroll
  for (int rr = 0; rr < 4; ++rr) {
    int r = rr * 16 + r0;
    float4 v = *(const float4*)(src + (size_t)(t0 + r) * DD + d0 + c4 * 4);
    tile[r][c4 * 4 + 0] = v.x;
    tile[r][c4 * 4 + 1] = v.y;
    tile[r][c4 * 4 + 2] = v.z;
    tile[r][c4 * 4 + 3] = v.w;
    bf16x4 o;
    o[0] = (bf16)v.x; o[1] = (bf16)v.y; o[2] = (bf16)v.z; o[3] = (bf16)v.w;
    *(bf16x4*)(dstb + (size_t)(t0 + r) * DD + d0 + c4 * 4) = o;
  }
  __syncthreads();
  int tc = tid & 7, dr0 = tid >> 3;
#pragma unroll
  for (int rr = 0; rr < 2; ++rr) {
    int dr = rr * 32 + dr0;
    bf16x8 o;
#pragma unroll
    for (int e = 0; e < 8; ++e) o[e] = (bf16)tile[tc * 8 + e][dr];
    *(bf16x8*)(dstT + (size_t)(d0 + dr) * TT + t0 + tc * 8) = o;
  }
}

// Wq,Wk fp32 [256,2048] -> stacked bf16 [512,2048]; bq,bk -> bqk fp32[512]
__global__ __launch_bounds__(256) void conv_w(
    const float* __restrict__ Wq, const float* __restrict__ Wk,
    const float* __restrict__ bq, const float* __restrict__ bk,
    bf16* __restrict__ Wqkb, float* __restrict__ bqk) {
  int i = blockIdx.x * 256 + threadIdx.x;
  float4 q = *(const float4*)(Wq + (size_t)i * 4);
  float4 k = *(const float4*)(Wk + (size_t)i * 4);
  bf16x4 qo, ko;
  qo[0] = (bf16)q.x; qo[1] = (bf16)q.y; qo[2] = (bf16)q.z; qo[3] = (bf16)q.w;
  ko[0] = (bf16)k.x; ko[1] = (bf16)k.y; ko[2] = (bf16)k.z; ko[3] = (bf16)k.w;
  *(bf16x4*)(Wqkb + (size_t)i * 4) = qo;
  *(bf16x4*)(Wqkb + (size_t)BOTC * DD + (size_t)i * 4) = ko;
  if (blockIdx.x == 0) {
    bqk[threadIdx.x] = bq[threadIdx.x];
    bqk[256 + threadIdx.x] = bk[threadIdx.x];
  }
}

// one block per row i: softmax over valid prefix (j < i-3) of S (bf16), then
// combined = 0.7*decay + 0.3*softmax written over the FULL row.
__global__ __launch_bounds__(256) void softmax_combine(
    bf16* __restrict__ S, const float* __restrict__ decay) {
  int b = blockIdx.y, i = blockIdx.x;
  bf16* srow = S + ((size_t)b * TT + i) * TT;
  const float* drow = decay + ((size_t)b * TT + i) * TT;
  int t = threadIdx.x;
  int lane = t & 63, w = t >> 6;
  const int valid = i - 3;
  const int nc = valid > 0 ? (valid + 7) >> 3 : 0;

  float p[2][8];
  float inv = 0.f, pc = 0.f;

  if (valid > 0) {
    float s[2][8];
#pragma unroll
    for (int u = 0; u < 2; ++u) {
      int c = u * 256 + t;
      if (c < nc) {
        bf16x8 sv = *(const bf16x8*)(srow + (size_t)c * 8);
#pragma unroll
        for (int e = 0; e < 8; ++e) {
          int j = c * 8 + e;
          s[u][e] = j < valid ? (float)sv[e] : -INFINITY;
        }
      } else {
#pragma unroll
        for (int e = 0; e < 8; ++e) s[u][e] = -INFINITY;
      }
    }
    float m = s[0][0];
#pragma unroll
    for (int u = 0; u < 2; ++u)
#pragma unroll
      for (int e = 0; e < 8; ++e) m = fmaxf(m, s[u][e]);
#pragma unroll
    for (int off = 32; off > 0; off >>= 1) m = fmaxf(m, __shfl_xor(m, off));
    __shared__ float redm[4], reds[4];
    if (lane == 0) redm[w] = m;
    __syncthreads();
    m = fmaxf(fmaxf(redm[0], redm[1]), fmaxf(redm[2], redm[3]));

    float sum = 0.f;
#pragma unroll
    for (int u = 0; u < 2; ++u)
#pragma unroll
      for (int e = 0; e < 8; ++e) {
        p[u][e] = __expf(s[u][e] - m);
        sum += p[u][e];
      }
#pragma unroll
    for (int off = 32; off > 0; off >>= 1) sum += __shfl_xor(sum, off);
    if (lane == 0) reds[w] = sum;
    __syncthreads();
    sum = reds[0] + reds[1] + reds[2] + reds[3];
    inv = 0.3f / sum;
  } else {
    pc = 0.3f / 4096.0f;
#pragma unroll
    for (int u = 0; u < 2; ++u)
#pragma unroll
      for (int e = 0; e < 8; ++e) p[u][e] = 0.f;
  }

#pragma unroll
  for (int u = 0; u < 2; ++u) {
    int c = u * 256 + t;
    const float4* d4 = (const float4*)(drow + (size_t)c * 8);
    float4 da = d4[0], db = d4[1];
    float pv[8];
#pragma unroll
    for (int e = 0; e < 8; ++e) pv[e] = p[u][e] * inv + pc;
    bf16x8 o;
    o[0] = (bf16)(0.7f * da.x + pv[0]);
    o[1] = (bf16)(0.7f * da.y + pv[1]);
    o[2] = (bf16)(0.7f * da.z + pv[2]);
    o[3] = (bf16)(0.7f * da.w + pv[3]);
    o[4] = (bf16)(0.7f * db.x + pv[4]);
    o[5] = (bf16)(0.7f * db.y + pv[5]);
    o[6] = (bf16)(0.7f * db.z + pv[6]);
    o[7] = (bf16)(0.7f * db.w + pv[7]);
    *(bf16x8*)(srow + (size_t)c * 8) = o;
  }
}

extern "C" void kernel_launch(void* const* d_in, const int* in_sizes, int n_in,
                              void* d_out, int out_size, void* d_ws, size_t ws_size,
                              hipStream_t stream) {
  (void)in_sizes; (void)n_in; (void)out_size; (void)ws_size;
  const float* hdc = (const float*)d_in[0];
  const float* decay = (const float*)d_in[1];
  const float* Wq = (const float*)d_in[2];
  const float* bq = (const float*)d_in[3];
  const float* Wk = (const float*)d_in[4];
  const float* bk = (const float*)d_in[5];
  float* out = (float*)d_out;

  char* ws = (char*)d_ws;
  bf16* hdc_b = (bf16*)ws; ws += (size_t)BB * TT * DD * 2;
  bf16* hdcT  = (bf16*)ws; ws += (size_t)BB * TT * DD * 2;
  bf16* Wqkb  = (bf16*)ws; ws += (size_t)2 * BOTC * DD * 2;
  float* bqk  = (float*)ws; ws += 2 * BOTC * 4;
  bf16* qk    = (bf16*)ws; ws += (size_t)BB * TT * 2 * BOTC * 2;
  bf16* S     = (bf16*)ws; ws += (size_t)BB * TT * TT * 2;

  // 1) hdc -> bf16 (+transposed); weights -> stacked bf16 + bias vec
  conv_transpose<<<dim3(DD / 64, TT / 64, BB), 256, 0, stream>>>(hdc, hdc_b, hdcT);
  conv_w<<<dim3(BOTC * DD / 1024), 256, 0, stream>>>(Wq, Wk, bq, bk, Wqkb, bqk);

  // 2) fused projection: [q|k] = hdc @ [Wq;Wk]^T + [bq;bk]   (M=B*T, N=512, K=2048)
  gemm_bt<1><<<dim3((2 * BOTC) / BN, (BB * TT) / BM, 1), 256, 0, stream>>>(
      hdc_b, Wqkb, qk, bqk, BB * TT, 2 * BOTC, DD, DD, DD, 0, 0, 0, 1.0f);

  // 3) scores = (q@k^T)/16 masked, bf16; masked tiles skipped entirely
  gemm_bt<2><<<dim3(TT / BN, TT / BM, BB), 256, 0, stream>>>(
      qk, qk + BOTC, S, nullptr, TT, TT, BOTC, 2 * BOTC, 2 * BOTC,
      (long)TT * 2 * BOTC, (long)TT * 2 * BOTC, (long)TT * TT, 0.0625f);

  // 4) in-place: S <- 0.7*decay + 0.3*softmax(S)  (prefix-only read)
  softmax_combine<<<dim3(TT, BB), 256, 0, stream>>>(S, decay);

  // 5) out = combined @ hdc  (per batch M=T, N=D, K=T) — 256² 8-phase pipeline
  gemm256<<<dim3(DD / 256, TT / 256, BB), 512, 0, stream>>>(
      S, hdcT, out, DD, TT, TT, TT,
      (long)TT * TT, (long)DD * TT, (long)TT * DD);
}

// Round 4
// 881.952 us; speedup vs baseline: 1.1055x; 1.0277x over previous
//
#include <hip/hip_runtime.h>
#include <hip/hip_bf16.h>

#define BB 4
#define TT 4096
#define DD 2048
#define BOTC 256

typedef __bf16 bf16;
typedef __attribute__((ext_vector_type(4))) __bf16 bf16x4;
typedef __attribute__((ext_vector_type(8))) __bf16 bf16x8;
typedef __attribute__((ext_vector_type(4))) float f32x4;

constexpr int BM = 128, BN = 128, BK = 64;

__device__ __forceinline__ void async16(const void* g, bf16* l) {
  __builtin_amdgcn_global_load_lds((const __attribute__((address_space(1))) void*)g,
                                   (__attribute__((address_space(3))) void*)l, 16, 0, 0);
}

#define SBAR asm volatile("s_barrier" ::: "memory")
#define WAIT_LGKM0 asm volatile("s_waitcnt lgkmcnt(0)" ::: "memory")
#define WAIT_VM6 asm volatile("s_waitcnt vmcnt(6)" ::: "memory")
#define WAIT_VM0 asm volatile("s_waitcnt vmcnt(0)" ::: "memory")

// ---------------- 128x128 tile GEMM (projection EPI=1, scores EPI=2) ----------------
// C[m,n] = sum_k A[m,k]*B[n,k]  (row-major, K contiguous; ldA/ldB row strides)
template <int EPI>
__global__ __launch_bounds__(256) void gemm_bt(
    const bf16* __restrict__ A, const bf16* __restrict__ Bm, void* __restrict__ Cout,
    const float* __restrict__ bias, int M, int N, int K, int ldA, int ldB,
    long sAb, long sBb, long sCb, float scale) {
  const int b = blockIdx.z;
  const int m0 = blockIdx.y * BM;
  const int n0 = blockIdx.x * BN;
  const int tid = threadIdx.x;
  const int lane = tid & 63;
  const int w = tid >> 6;
  const int wm = (w >> 1) * 64;
  const int wn = (w & 1) * 64;

  if (EPI == 2 && n0 > m0) return;  // fully masked: never written, never read

  __shared__ bf16 As[BM * BK];
  __shared__ bf16 Bs[BN * BK];

  f32x4 acc[4][4] = {};

  const bf16* Arow = A + (size_t)b * sAb + (size_t)m0 * ldA;
  const bf16* Brow = Bm + (size_t)b * sBb + (size_t)n0 * ldB;

  for (int k0 = 0; k0 < K; k0 += BK) {
#pragma unroll
    for (int j = 0; j < 4; ++j) {
      int c = j * 256 + tid;
      int row = c >> 3, kc = c & 7;
      int gk = kc ^ (row & 7);
      async16(Arow + (size_t)row * ldA + k0 + gk * 8, As + (size_t)c * 8);
      async16(Brow + (size_t)row * ldB + k0 + gk * 8, Bs + (size_t)c * 8);
    }
    __syncthreads();
    bf16x8 af[4][2], bfr[4][2];
#pragma unroll
    for (int mi = 0; mi < 4; ++mi)
#pragma unroll
      for (int kk = 0; kk < 2; ++kk) {
        int row = wm + mi * 16 + (lane & 15);
        int kc = kk * 4 + (lane >> 4);
        af[mi][kk] = *(const bf16x8*)(As + ((size_t)row * 8 + (kc ^ (row & 7))) * 8);
      }
#pragma unroll
    for (int ni = 0; ni < 4; ++ni)
#pragma unroll
      for (int kk = 0; kk < 2; ++kk) {
        int row = wn + ni * 16 + (lane & 15);
        int kc = kk * 4 + (lane >> 4);
        bfr[ni][kk] = *(const bf16x8*)(Bs + ((size_t)row * 8 + (kc ^ (row & 7))) * 8);
      }
#pragma unroll
    for (int kk = 0; kk < 2; ++kk)
#pragma unroll
      for (int mi = 0; mi < 4; ++mi)
#pragma unroll
        for (int ni = 0; ni < 4; ++ni)
          acc[mi][ni] = __builtin_amdgcn_mfma_f32_16x16x32_bf16(af[mi][kk], bfr[ni][kk], acc[mi][ni], 0, 0, 0);
    __syncthreads();
  }

  const int lcol = lane & 15;
  const int lrow = (lane >> 4) * 4;

  if (EPI == 1) {
    bf16* C = (bf16*)Cout + (size_t)b * sCb;
#pragma unroll
    for (int mi = 0; mi < 4; ++mi) {
      int rbase = m0 + wm + mi * 16 + lrow;
#pragma unroll
      for (int ni = 0; ni < 4; ++ni) {
        int col = n0 + wn + ni * 16 + lcol;
        float bv = bias[col];
#pragma unroll
        for (int r = 0; r < 4; ++r)
          C[(size_t)(rbase + r) * N + col] = (bf16)(acc[mi][ni][r] + bv);
      }
    }
  } else {
    bf16* C = (bf16*)Cout + (size_t)b * sCb;
#pragma unroll
    for (int mi = 0; mi < 4; ++mi) {
      int rbase = m0 + wm + mi * 16 + lrow;
#pragma unroll
      for (int ni = 0; ni < 4; ++ni) {
        int col = n0 + wn + ni * 16 + lcol;
#pragma unroll
        for (int r = 0; r < 4; ++r) {
          int i = rbase + r;
          float v = acc[mi][ni][r] * scale;
          if (col > i - 4) v = -65000.0f;
          C[(size_t)i * N + col] = (bf16)v;
        }
      }
    }
  }
}

// ---------------- 256x256 8-phase GEMM (final combined @ hdc, fp32 out) ----------------
// Stage one 128x64 bf16 half-tile (16 KB): 512 threads x 2 chunks of 16B.
// Global k-chunk pre-swizzled (gk = kc ^ (row&7)); LDS dest linear (gload_lds rule).
__device__ __forceinline__ void stage_half(const bf16* __restrict__ src, int ld,
                                           bf16* lds, int tid) {
#pragma unroll
  for (int j = 0; j < 2; ++j) {
    int c = j * 512 + tid;
    int row = c >> 3;
    int gk = (c & 7) ^ (row & 7);
    async16(src + (size_t)row * ld + gk * 8, lds + (size_t)c * 8);
  }
}

__device__ __forceinline__ bf16x8 fragrd(const bf16* base, int lr, int kc) {
  return *(const bf16x8*)(base + ((size_t)lr * 8 + (kc ^ (lr & 7))) * 8);
}

__device__ __forceinline__ void load_b4(const bf16* base, int wn, int fr, int fq,
                                        bf16x8 (&bf_)[4][2]) {
#pragma unroll
  for (int ni = 0; ni < 4; ++ni)
#pragma unroll
    for (int kk = 0; kk < 2; ++kk)
      bf_[ni][kk] = fragrd(base, (wn & 1) * 64 + ni * 16 + fr, kk * 4 + fq);
}

__device__ __forceinline__ void load_a4(const bf16* base, int qm, int fr, int fq,
                                        bf16x8 (&a)[4][2]) {
#pragma unroll
  for (int mi = 0; mi < 4; ++mi)
#pragma unroll
    for (int kk = 0; kk < 2; ++kk)
      a[mi][kk] = fragrd(base, qm * 64 + mi * 16 + fr, kk * 4 + fq);
}

__device__ __forceinline__ void mfma_quad(f32x4 (&acc)[8][4], const bf16x8 (&a)[4][2],
                                          const bf16x8 (&bf_)[4][2], int qm, int qn) {
  __builtin_amdgcn_s_setprio(1);
#pragma unroll
  for (int kk = 0; kk < 2; ++kk)
#pragma unroll
    for (int mi = 0; mi < 4; ++mi)
#pragma unroll
      for (int ni = 0; ni < 2; ++ni)
        acc[qm * 4 + mi][qn * 2 + ni] = __builtin_amdgcn_mfma_f32_16x16x32_bf16(
            a[mi][kk], bf_[qn * 2 + ni][kk], acc[qm * 4 + mi][qn * 2 + ni], 0, 0, 0);
  __builtin_amdgcn_s_setprio(0);
}

// Schedule invariants (derived; see session journal):
//   reads: p0/p4 = all 8 B frags + A(qm0); p2/p6 = A(qm1)  ->
//     B halves consumed end of p0/p4, A halves end of p2/p6.
//   stage map (K-tile order B0,B1,A0,A1):
//     p0: K(2i+1).A1  p1: K(2i+2).B0  p2: K(2i+2).B1  p3: K(2i+2).A0
//     p4: K(2i+2).A1  p5: K(2i+3).B0  p6: K(2i+3).B1  p7: K(2i+3).A0
//   every write lands >=1 barrier after the region's last read.
//   vmcnt(6) at end of p3/p7 leaves exactly the 3 newest half-tiles in flight
//   and guarantees the next K-tile is fully in LDS.
// Grid is fixed at (8, 16, 4) = 512 blocks; swizzle uses compile-time masks only.
__global__ __launch_bounds__(512, 2) void gemm256(
    const bf16* __restrict__ A, const bf16* __restrict__ Bm, float* __restrict__ C,
    int N, int K, int ldA, int ldB, long sAb, long sBb, long sCb) {
  // T1: XCD-chunked swizzle (bijective, nwg=512 % 8 == 0). HW round-robins h over
  // 8 XCDs; remap so XCD x owns logical tiles l in [64x, 64x+64) = an 8x8 (by,bx)
  // block of one batch -> A panels fetched once chip-wide, B panels twice; per-XCD
  // working set ~512 KB << 4 MiB L2.
  const int h = blockIdx.x + 8 * (blockIdx.y + 16 * blockIdx.z);  // 0..511
  const int l = ((h & 7) << 6) + (h >> 3);
  const int bx = l & 7;          // l % gridDim.x
  const int lt = l >> 3;
  const int by = lt & 15;        // % gridDim.y
  const int b = lt >> 4;
  const int m0 = by * 256;
  const int n0 = bx * 256;
  const int tid = threadIdx.x;
  const int lane = tid & 63;
  const int w = tid >> 6;
  const int wm = w >> 2;   // 0..1: A half / output row half
  const int wn = w & 3;    // 0..3: output col quarter
  const int fr = lane & 15;
  const int fq = lane >> 4;
  const int bh = wn >> 1;
  const int NKT = K >> 6;  // K-tiles of 64
  const int NI = K >> 7;   // iterations (2 K-tiles each)

  __shared__ bf16 sA[2][2][8192];  // [buf][half][128*64]
  __shared__ bf16 sB[2][2][8192];

  const bf16* Ab = A + (size_t)b * sAb + (size_t)m0 * ldA;
  const bf16* Bb = Bm + (size_t)b * sBb + (size_t)n0 * ldB;

  f32x4 acc[8][4] = {};
  bf16x8 a[4][2], bf_[4][2];

  // prologue: K0 {B0,B1,A0,A1} then K1 {B0,B1,A0} = 7 half-tiles (14 loads)
  stage_half(Bb, ldB, &sB[0][0][0], tid);
  stage_half(Bb + (size_t)128 * ldB, ldB, &sB[0][1][0], tid);
  stage_half(Ab, ldA, &sA[0][0][0], tid);
  stage_half(Ab + (size_t)128 * ldA, ldA, &sA[0][1][0], tid);
  stage_half(Bb + 64, ldB, &sB[1][0][0], tid);
  stage_half(Bb + (size_t)128 * ldB + 64, ldB, &sB[1][1][0], tid);
  stage_half(Ab + 64, ldA, &sA[1][0][0], tid);
  WAIT_VM6;  // 8 oldest (= all of K0) landed
  SBAR;

  for (int i = 0; i < NI; ++i) {
    const size_t kA1 = (size_t)(2 * i + 1) * 64;
    int t2 = 2 * i + 2; if (t2 > NKT - 1) t2 = NKT - 1;  // tail clamp: redundant
    int t3 = 2 * i + 3; if (t3 > NKT - 1) t3 = NKT - 1;  // re-loads keep vmcnt exact
    const size_t k2 = (size_t)t2 * 64, k3 = (size_t)t3 * 64;

    // p0
    load_b4(&sB[0][bh][0], wn, fr, fq, bf_);
    load_a4(&sA[0][wm][0], 0, fr, fq, a);
    stage_half(Ab + (size_t)128 * ldA + kA1, ldA, &sA[1][1][0], tid);
    SBAR; WAIT_LGKM0; __builtin_amdgcn_sched_barrier(0);
    mfma_quad(acc, a, bf_, 0, 0);
    SBAR;
    // p1
    stage_half(Bb + k2, ldB, &sB[0][0][0], tid);
    SBAR;
    mfma_quad(acc, a, bf_, 0, 1);
    SBAR;
    // p2
    load_a4(&sA[0][wm][0], 1, fr, fq, a);
    stage_half(Bb + (size_t)128 * ldB + k2, ldB, &sB[0][1][0], tid);
    SBAR; WAIT_LGKM0; __builtin_amdgcn_sched_barrier(0);
    mfma_quad(acc, a, bf_, 1, 0);
    SBAR;
    // p3
    stage_half(Ab + k2, ldA, &sA[0][0][0], tid);
    SBAR;
    mfma_quad(acc, a, bf_, 1, 1);
    WAIT_VM6;  // K(2i+1) fully in LDS
    SBAR;
    // p4
    load_b4(&sB[1][bh][0], wn, fr, fq, bf_);
    load_a4(&sA[1][wm][0], 0, fr, fq, a);
    stage_half(Ab + (size_t)128 * ldA + k2, ldA, &sA[0][1][0], tid);
    SBAR; WAIT_LGKM0; __builtin_amdgcn_sched_barrier(0);
    mfma_quad(acc, a, bf_, 0, 0);
    SBAR;
    // p5
    stage_half(Bb + k3, ldB, &sB[1][0][0], tid);
    SBAR;
    mfma_quad(acc, a, bf_, 0, 1);
    SBAR;
    // p6
    load_a4(&sA[1][wm][0], 1, fr, fq, a);
    stage_half(Bb + (size_t)128 * ldB + k3, ldB, &sB[1][1][0], tid);
    SBAR; WAIT_LGKM0; __builtin_amdgcn_sched_barrier(0);
    mfma_quad(acc, a, bf_, 1, 0);
    SBAR;
    // p7
    stage_half(Ab + k3, ldA, &sA[1][0][0], tid);
    SBAR;
    mfma_quad(acc, a, bf_, 1, 1);
    WAIT_VM6;  // K(2i+2) fully in LDS
    SBAR;
  }

  WAIT_VM0;  // drain tail re-loads before epilogue

  float* Cb = C + (size_t)b * sCb;
  const int lrow = fq * 4;
#pragma unroll
  for (int mi = 0; mi < 8; ++mi) {
    int rbase = m0 + wm * 128 + mi * 16 + lrow;
#pragma unroll
    for (int ni = 0; ni < 4; ++ni) {
      int col = n0 + wn * 64 + ni * 16 + fr;
#pragma unroll
      for (int r = 0; r < 4; ++r)
        Cb[(size_t)(rbase + r) * N + col] = acc[mi][ni][r];
    }
  }
}

// fp32 [B,T,D] -> bf16 [B,T,D] and bf16 transposed [B,D,T], 64x64 tiles, wide stores
__global__ __launch_bounds__(256) void conv_transpose(
    const float* __restrict__ hdc, bf16* __restrict__ hb, bf16* __restrict__ hT) {
  __shared__ float tile[64][65];
  int b = blockIdx.z;
  int d0 = blockIdx.x * 64, t0 = blockIdx.y * 64;
  int tid = threadIdx.x;
  const float* src = hdc + (size_t)b * TT * DD;
  bf16* dstb = hb + (size_t)b * TT * DD;
  bf16* dstT = hT + (size_t)b * DD * TT;
  int c4 = tid & 15, r0 = tid >> 4;
#pragma unroll
  for (int rr = 0; rr < 4; ++rr) {
    int r = rr * 16 + r0;
    float4 v = *(const float4*)(src + (size_t)(t0 + r) * DD + d0 + c4 * 4);
    tile[r][c4 * 4 + 0] = v.x;
    tile[r][c4 * 4 + 1] = v.y;
    tile[r][c4 * 4 + 2] = v.z;
    tile[r][c4 * 4 + 3] = v.w;
    bf16x4 o;
    o[0] = (bf16)v.x; o[1] = (bf16)v.y; o[2] = (bf16)v.z; o[3] = (bf16)v.w;
    *(bf16x4*)(dstb + (size_t)(t0 + r) * DD + d0 + c4 * 4) = o;
  }
  __syncthreads();
  int tc = tid & 7, dr0 = tid >> 3;
#pragma unroll
  for (int rr = 0; rr < 2; ++rr) {
    int dr = rr * 32 + dr0;
    bf16x8 o;
#pragma unroll
    for (int e = 0; e < 8; ++e) o[e] = (bf16)tile[tc * 8 + e][dr];
    *(bf16x8*)(dstT + (size_t)(d0 + dr) * TT + t0 + tc * 8) = o;
  }
}

// Wq,Wk fp32 [256,2048] -> stacked bf16 [512,2048]; bq,bk -> bqk fp32[512]
__global__ __launch_bounds__(256) void conv_w(
    const float* __restrict__ Wq, const float* __restrict__ Wk,
    const float* __restrict__ bq, const float* __restrict__ bk,
    bf16* __restrict__ Wqkb, float* __restrict__ bqk) {
  int i = blockIdx.x * 256 + threadIdx.x;
  float4 q = *(const float4*)(Wq + (size_t)i * 4);
  float4 k = *(const float4*)(Wk + (size_t)i * 4);
  bf16x4 qo, ko;
  qo[0] = (bf16)q.x; qo[1] = (bf16)q.y; qo[2] = (bf16)q.z; qo[3] = (bf16)q.w;
  ko[0] = (bf16)k.x; ko[1] = (bf16)k.y; ko[2] = (bf16)k.z; ko[3] = (bf16)k.w;
  *(bf16x4*)(Wqkb + (size_t)i * 4) = qo;
  *(bf16x4*)(Wqkb + (size_t)BOTC * DD + (size_t)i * 4) = ko;
  if (blockIdx.x == 0) {
    bqk[threadIdx.x] = bq[threadIdx.x];
    bqk[256 + threadIdx.x] = bk[threadIdx.x];
  }
}

// one block per row i: softmax over valid prefix (j < i-3) of S (bf16), then
// combined = 0.7*decay + 0.3*softmax written over the FULL row.
__global__ __launch_bounds__(256) void softmax_combine(
    bf16* __restrict__ S, const float* __restrict__ decay) {
  int b = blockIdx.y, i = blockIdx.x;
  bf16* srow = S + ((size_t)b * TT + i) * TT;
  const float* drow = decay + ((size_t)b * TT + i) * TT;
  int t = threadIdx.x;
  int lane = t & 63, w = t >> 6;
  const int valid = i - 3;
  const int nc = valid > 0 ? (valid + 7) >> 3 : 0;

  float p[2][8];
  float inv = 0.f, pc = 0.f;

  if (valid > 0) {
    float s[2][8];
#pragma unroll
    for (int u = 0; u < 2; ++u) {
      int c = u * 256 + t;
      if (c < nc) {
        bf16x8 sv = *(const bf16x8*)(srow + (size_t)c * 8);
#pragma unroll
        for (int e = 0; e < 8; ++e) {
          int j = c * 8 + e;
          s[u][e] = j < valid ? (float)sv[e] : -INFINITY;
        }
      } else {
#pragma unroll
        for (int e = 0; e < 8; ++e) s[u][e] = -INFINITY;
      }
    }
    float m = s[0][0];
#pragma unroll
    for (int u = 0; u < 2; ++u)
#pragma unroll
      for (int e = 0; e < 8; ++e) m = fmaxf(m, s[u][e]);
#pragma unroll
    for (int off = 32; off > 0; off >>= 1) m = fmaxf(m, __shfl_xor(m, off));
    __shared__ float redm[4], reds[4];
    if (lane == 0) redm[w] = m;
    __syncthreads();
    m = fmaxf(fmaxf(redm[0], redm[1]), fmaxf(redm[2], redm[3]));

    float sum = 0.f;
#pragma unroll
    for (int u = 0; u < 2; ++u)
#pragma unroll
      for (int e = 0; e < 8; ++e) {
        p[u][e] = __expf(s[u][e] - m);
        sum += p[u][e];
      }
#pragma unroll
    for (int off = 32; off > 0; off >>= 1) sum += __shfl_xor(sum, off);
    if (lane == 0) reds[w] = sum;
    __syncthreads();
    sum = reds[0] + reds[1] + reds[2] + reds[3];
    inv = 0.3f / sum;
  } else {
    pc = 0.3f / 4096.0f;
#pragma unroll
    for (int u = 0; u < 2; ++u)
#pragma unroll
      for (int e = 0; e < 8; ++e) p[u][e] = 0.f;
  }

#pragma unroll
  for (int u = 0; u < 2; ++u) {
    int c = u * 256 + t;
    const float4* d4 = (const float4*)(drow + (size_t)c * 8);
    float4 da = d4[0], db = d4[1];
    float pv[8];
#pragma unroll
    for (int e = 0; e < 8; ++e) pv[e] = p[u][e] * inv + pc;
    bf16x8 o;
    o[0] = (bf16)(0.7f * da.x + pv[0]);
    o[1] = (bf16)(0.7f * da.y + pv[1]);
    o[2] = (bf16)(0.7f * da.z + pv[2]);
    o[3] = (bf16)(0.7f * da.w + pv[3]);
    o[4] = (bf16)(0.7f * db.x + pv[4]);
    o[5] = (bf16)(0.7f * db.y + pv[5]);
    o[6] = (bf16)(0.7f * db.z + pv[6]);
    o[7] = (bf16)(0.7f * db.w + pv[7]);
    *(bf16x8*)(srow + (size_t)c * 8) = o;
  }
}

extern "C" void kernel_launch(void* const* d_in, const int* in_sizes, int n_in,
                              void* d_out, int out_size, void* d_ws, size_t ws_size,
                              hipStream_t stream) {
  (void)in_sizes; (void)n_in; (void)out_size; (void)ws_size;
  const float* hdc = (const float*)d_in[0];
  const float* decay = (const float*)d_in[1];
  const float* Wq = (const float*)d_in[2];
  const float* bq = (const float*)d_in[3];
  const float* Wk = (const float*)d_in[4];
  const float* bk = (const float*)d_in[5];
  float* out = (float*)d_out;

  char* ws = (char*)d_ws;
  bf16* hdc_b = (bf16*)ws; ws += (size_t)BB * TT * DD * 2;
  bf16* hdcT  = (bf16*)ws; ws += (size_t)BB * TT * DD * 2;
  bf16* Wqkb  = (bf16*)ws; ws += (size_t)2 * BOTC * DD * 2;
  float* bqk  = (float*)ws; ws += 2 * BOTC * 4;
  bf16* qk    = (bf16*)ws; ws += (size_t)BB * TT * 2 * BOTC * 2;
  bf16* S     = (bf16*)ws; ws += (size_t)BB * TT * TT * 2;

  // 1) hdc -> bf16 (+transposed); weights -> stacked bf16 + bias vec
  conv_transpose<<<dim3(DD / 64, TT / 64, BB), 256, 0, stream>>>(hdc, hdc_b, hdcT);
  conv_w<<<dim3(BOTC * DD / 1024), 256, 0, stream>>>(Wq, Wk, bq, bk, Wqkb, bqk);

  // 2) fused projection: [q|k] = hdc @ [Wq;Wk]^T + [bq;bk]   (M=B*T, N=512, K=2048)
  gemm_bt<1><<<dim3((2 * BOTC) / BN, (BB * TT) / BM, 1), 256, 0, stream>>>(
      hdc_b, Wqkb, qk, bqk, BB * TT, 2 * BOTC, DD, DD, DD, 0, 0, 0, 1.0f);

  // 3) scores = (q@k^T)/16 masked, bf16; masked tiles skipped entirely
  gemm_bt<2><<<dim3(TT / BN, TT / BM, BB), 256, 0, stream>>>(
      qk, qk + BOTC, S, nullptr, TT, TT, BOTC, 2 * BOTC, 2 * BOTC,
      (long)TT * 2 * BOTC, (long)TT * 2 * BOTC, (long)TT * TT, 0.0625f);

  // 4) in-place: S <- 0.7*decay + 0.3*softmax(S)  (prefix-only read)
  softmax_combine<<<dim3(TT, BB), 256, 0, stream>>>(S, decay);

  // 5) out = combined @ hdc  (per batch M=T, N=D, K=T) — 256² 8-phase + XCD swizzle
  gemm256<<<dim3(DD / 256, TT / 256, BB), 512, 0, stream>>>(
      S, hdcT, out, DD, TT, TT, TT,
      (long)TT * TT, (long)DD * TT, (long)TT * DD);
}